// Round 1
// baseline (22.583 us; speedup 1.0000x reference)
//
#include <hip/hip_runtime.h>
#include <math.h>

#define H 4096
#define D 104

// Kernel 1: h_t = sigmoid(Uw @ hidden + Ub + Ww @ line + Wb)
// grid = H/4 blocks of 256 threads (4 waves); one row per wave.
__global__ void __launch_bounds__(256) k_hidden(
    const float* __restrict__ Uw, const float* __restrict__ hidden,
    const float* __restrict__ Ub, const float* __restrict__ Ww,
    const float* __restrict__ line, const float* __restrict__ Wb,
    float* __restrict__ h_out)
{
    const int wave = threadIdx.x >> 6;
    const int lane = threadIdx.x & 63;
    const int row  = blockIdx.x * 4 + wave;

    const float4* __restrict__ u  = (const float4*)(Uw + (size_t)row * H);
    const float4* __restrict__ hv = (const float4*)hidden;

    float acc = 0.f;
    // H/4 = 1024 float4 per row; 64 lanes -> 16 iterations
    #pragma unroll 4
    for (int j4 = lane; j4 < H / 4; j4 += 64) {
        float4 a = u[j4];
        float4 b = hv[j4];
        acc += a.x * b.x + a.y * b.y + a.z * b.z + a.w * b.w;
    }

    // Ww @ line tail: D=104 -> 26 float4 per row (416B rows, 16B aligned)
    const float4* __restrict__ w  = (const float4*)(Ww + (size_t)row * D);
    const float4* __restrict__ lv = (const float4*)line;
    if (lane < D / 4) {
        float4 a = w[lane];
        float4 b = lv[lane];
        acc += a.x * b.x + a.y * b.y + a.z * b.z + a.w * b.w;
    }

    // wave (64-lane) reduction
    #pragma unroll
    for (int off = 32; off; off >>= 1)
        acc += __shfl_down(acc, off, 64);

    if (lane == 0) {
        float v = acc + Ub[row] + Wb[row];
        h_out[row] = 1.f / (1.f + expf(-v));
    }
}

// Kernel 2: pred = Vw @ h_t + Vb, then segmented log_softmax.
// grid = 10 blocks (one per segment), 832 threads (13 waves); wave w
// computes dot for row (seg_start + w); wave 0 does the log_softmax.
__global__ void __launch_bounds__(832) k_pred(
    const float* __restrict__ Vw, const float* __restrict__ h_t,
    const float* __restrict__ Vb, float* __restrict__ out)
{
    __shared__ float s_pred[13];
    const int seg_a[11] = {0, 13, 26, 39, 48, 52, 65, 78, 91, 100, 104};

    const int s    = blockIdx.x;
    const int a    = seg_a[s];
    const int len  = seg_a[s + 1] - a;
    const int wave = threadIdx.x >> 6;
    const int lane = threadIdx.x & 63;

    if (wave < len) {
        const int d = a + wave;
        const float4* __restrict__ v  = (const float4*)(Vw + (size_t)d * H);
        const float4* __restrict__ hv = (const float4*)h_t;
        float acc = 0.f;
        #pragma unroll 4
        for (int j4 = lane; j4 < H / 4; j4 += 64) {
            float4 x = v[j4];
            float4 y = hv[j4];
            acc += x.x * y.x + x.y * y.y + x.z * y.z + x.w * y.w;
        }
        #pragma unroll
        for (int off = 32; off; off >>= 1)
            acc += __shfl_down(acc, off, 64);
        if (lane == 0) s_pred[wave] = acc + Vb[d];
    }
    __syncthreads();

    if (wave == 0) {
        float x = (lane < len) ? s_pred[lane] : -INFINITY;
        float m = x;
        #pragma unroll
        for (int off = 32; off; off >>= 1)
            m = fmaxf(m, __shfl_xor(m, off, 64));
        float e = (lane < len) ? expf(x - m) : 0.f;
        float ssum = e;
        #pragma unroll
        for (int off = 32; off; off >>= 1)
            ssum += __shfl_xor(ssum, off, 64);
        if (lane < len) out[a + lane] = x - m - logf(ssum);
    }
}

extern "C" void kernel_launch(void* const* d_in, const int* in_sizes, int n_in,
                              void* d_out, int out_size, void* d_ws, size_t ws_size,
                              hipStream_t stream) {
    const float* line   = (const float*)d_in[0];
    const float* hidden = (const float*)d_in[1];
    const float* Uw     = (const float*)d_in[2];
    const float* Ub     = (const float*)d_in[3];
    const float* Ww     = (const float*)d_in[4];
    const float* Wb     = (const float*)d_in[5];
    const float* Vw     = (const float*)d_in[6];
    const float* Vb     = (const float*)d_in[7];

    float* out = (float*)d_out;       // [0:104) pred_logsoft, [104:4200) h_t
    float* h_t = out + D;

    k_hidden<<<H / 4, 256, 0, stream>>>(Uw, hidden, Ub, Ww, line, Wb, h_t);
    k_pred<<<10, 832, 0, stream>>>(Vw, h_t, Vb, out);
}

// Round 2
// 21.904 us; speedup vs baseline: 1.0310x; 1.0310x over previous
//
#include <hip/hip_runtime.h>
#include <math.h>

#define H 4096
#define D 104

// Kernel 1: h_t = sigmoid(Uw @ hidden + Ub + Ww @ line + Wb)
// grid = H/4 blocks of 256 threads (4 waves); one row per wave.
__global__ void __launch_bounds__(256) k_hidden(
    const float* __restrict__ Uw, const float* __restrict__ hidden,
    const float* __restrict__ Ub, const float* __restrict__ Ww,
    const float* __restrict__ line, const float* __restrict__ Wb,
    float* __restrict__ h_out)
{
    const int wave = threadIdx.x >> 6;
    const int lane = threadIdx.x & 63;
    const int row  = blockIdx.x * 4 + wave;

    const float4* __restrict__ u  = (const float4*)(Uw + (size_t)row * H);
    const float4* __restrict__ hv = (const float4*)hidden;

    float acc = 0.f;
    // H/4 = 1024 float4 per row; 64 lanes -> 16 iterations
    #pragma unroll 4
    for (int j4 = lane; j4 < H / 4; j4 += 64) {
        float4 a = u[j4];
        float4 b = hv[j4];
        acc += a.x * b.x + a.y * b.y + a.z * b.z + a.w * b.w;
    }

    // Ww @ line tail: D=104 -> 26 float4 per row
    const float4* __restrict__ w  = (const float4*)(Ww + (size_t)row * D);
    const float4* __restrict__ lv = (const float4*)line;
    if (lane < D / 4) {
        float4 a = w[lane];
        float4 b = lv[lane];
        acc += a.x * b.x + a.y * b.y + a.z * b.z + a.w * b.w;
    }

    #pragma unroll
    for (int off = 32; off; off >>= 1)
        acc += __shfl_down(acc, off, 64);

    if (lane == 0) {
        float v = acc + Ub[row] + Wb[row];
        h_out[row] = 1.f / (1.f + expf(-v));
    }
}

// Kernel 2a: pred[d] = Vw[d,:] . h_t + Vb[d], one block per row d.
__global__ void __launch_bounds__(256) k_pred_rows(
    const float* __restrict__ Vw, const float* __restrict__ h_t,
    const float* __restrict__ Vb, float* __restrict__ pred)
{
    __shared__ float r[4];
    const int d    = blockIdx.x;
    const int tid  = threadIdx.x;
    const int wave = tid >> 6;
    const int lane = tid & 63;

    const float4* __restrict__ v  = (const float4*)(Vw + (size_t)d * H);
    const float4* __restrict__ hv = (const float4*)h_t;

    float acc = 0.f;
    #pragma unroll
    for (int j4 = tid; j4 < H / 4; j4 += 256) {   // 4 iterations
        float4 x = v[j4];
        float4 y = hv[j4];
        acc += x.x * y.x + x.y * y.y + x.z * y.z + x.w * y.w;
    }
    #pragma unroll
    for (int off = 32; off; off >>= 1)
        acc += __shfl_down(acc, off, 64);
    if (lane == 0) r[wave] = acc;
    __syncthreads();
    if (tid == 0)
        pred[d] = r[0] + r[1] + r[2] + r[3] + Vb[d];
}

// Kernel 2b: 10 independent segmented log_softmaxes; wave s = segment s.
__global__ void __launch_bounds__(640) k_logsoftmax(
    const float* __restrict__ pred, float* __restrict__ out)
{
    const int seg_a[11] = {0, 13, 26, 39, 48, 52, 65, 78, 91, 100, 104};
    const int s    = threadIdx.x >> 6;
    const int lane = threadIdx.x & 63;
    const int a    = seg_a[s];
    const int len  = seg_a[s + 1] - a;

    float x = (lane < len) ? pred[a + lane] : -INFINITY;
    float m = x;
    #pragma unroll
    for (int off = 32; off; off >>= 1)
        m = fmaxf(m, __shfl_xor(m, off, 64));
    float e = (lane < len) ? expf(x - m) : 0.f;
    float ssum = e;
    #pragma unroll
    for (int off = 32; off; off >>= 1)
        ssum += __shfl_xor(ssum, off, 64);
    if (lane < len) out[a + lane] = x - m - logf(ssum);
}

extern "C" void kernel_launch(void* const* d_in, const int* in_sizes, int n_in,
                              void* d_out, int out_size, void* d_ws, size_t ws_size,
                              hipStream_t stream) {
    const float* line   = (const float*)d_in[0];
    const float* hidden = (const float*)d_in[1];
    const float* Uw     = (const float*)d_in[2];
    const float* Ub     = (const float*)d_in[3];
    const float* Ww     = (const float*)d_in[4];
    const float* Wb     = (const float*)d_in[5];
    const float* Vw     = (const float*)d_in[6];
    const float* Vb     = (const float*)d_in[7];

    float* out  = (float*)d_out;      // [0:104) pred_logsoft, [104:4200) h_t
    float* h_t  = out + D;
    float* pred = (float*)d_ws;       // scratch: 104 floats

    k_hidden<<<H / 4, 256, 0, stream>>>(Uw, hidden, Ub, Ww, line, Wb, h_t);
    k_pred_rows<<<D, 256, 0, stream>>>(Vw, h_t, Vb, pred);
    k_logsoftmax<<<1, 640, 0, stream>>>(pred, out);
}

// Round 4
// 20.856 us; speedup vs baseline: 1.0828x; 1.0502x over previous
//
#include <hip/hip_runtime.h>
#include <math.h>

#define H 4096
#define D 104

typedef float f32x4 __attribute__((ext_vector_type(4)));

// Kernel 1: h_t = sigmoid(Uw @ hidden + Ub + Ww @ line + Wb)
// grid = H/4 blocks of 256 threads (4 waves); one row per wave.
// hidden is staged in LDS (16 KB) so the Uw HBM stream doesn't fight the
// hidden re-reads for L1/L2; Uw loads are nontemporal (stream-once).
__global__ void __launch_bounds__(256) k_hidden(
    const float* __restrict__ Uw, const float* __restrict__ hidden,
    const float* __restrict__ Ub, const float* __restrict__ Ww,
    const float* __restrict__ line, const float* __restrict__ Wb,
    float* __restrict__ h_out)
{
    __shared__ f32x4 s_h4[H / 4];          // 16 KB

    const int tid  = threadIdx.x;
    const int wave = tid >> 6;
    const int lane = tid & 63;
    const int row  = blockIdx.x * 4 + wave;

    // cooperative stage of hidden: 1024 float4 / 256 threads = 4 each
    const f32x4* __restrict__ hv = (const f32x4*)hidden;
    #pragma unroll
    for (int i = tid; i < H / 4; i += 256)
        s_h4[i] = hv[i];
    __syncthreads();

    const f32x4* __restrict__ u = (const f32x4*)(Uw + (size_t)row * H);

    float acc0 = 0.f, acc1 = 0.f;
    // 16 float4 per lane; 2 accumulators, unroll 4
    #pragma unroll 4
    for (int k = 0; k < 16; k += 2) {
        const int j0 = lane + k * 64;
        const int j1 = j0 + 64;
        f32x4 a0 = __builtin_nontemporal_load(&u[j0]);
        f32x4 b0 = s_h4[j0];
        f32x4 a1 = __builtin_nontemporal_load(&u[j1]);
        f32x4 b1 = s_h4[j1];
        acc0 += a0.x * b0.x + a0.y * b0.y + a0.z * b0.z + a0.w * b0.w;
        acc1 += a1.x * b1.x + a1.y * b1.y + a1.z * b1.z + a1.w * b1.w;
    }
    float acc = acc0 + acc1;

    // Ww @ line tail: D=104 -> 26 float4 per row
    const f32x4* __restrict__ w  = (const f32x4*)(Ww + (size_t)row * D);
    const f32x4* __restrict__ lv = (const f32x4*)line;
    if (lane < D / 4) {
        f32x4 a = __builtin_nontemporal_load(&w[lane]);
        f32x4 b = lv[lane];
        acc += a.x * b.x + a.y * b.y + a.z * b.z + a.w * b.w;
    }

    #pragma unroll
    for (int off = 32; off; off >>= 1)
        acc += __shfl_down(acc, off, 64);

    if (lane == 0) {
        float v = acc + Ub[row] + Wb[row];
        h_out[row] = 1.f / (1.f + expf(-v));
    }
}

// Kernel 2a: pred[d] = Vw[d,:] . h_t + Vb[d], one block per row d.
__global__ void __launch_bounds__(256) k_pred_rows(
    const float* __restrict__ Vw, const float* __restrict__ h_t,
    const float* __restrict__ Vb, float* __restrict__ pred)
{
    __shared__ float r[4];
    const int d    = blockIdx.x;
    const int tid  = threadIdx.x;
    const int wave = tid >> 6;
    const int lane = tid & 63;

    const f32x4* __restrict__ v  = (const f32x4*)(Vw + (size_t)d * H);
    const f32x4* __restrict__ hv = (const f32x4*)h_t;

    float acc = 0.f;
    #pragma unroll
    for (int j4 = tid; j4 < H / 4; j4 += 256) {   // 4 iterations
        f32x4 x = __builtin_nontemporal_load(&v[j4]);
        f32x4 y = hv[j4];
        acc += x.x * y.x + x.y * y.y + x.z * y.z + x.w * y.w;
    }
    #pragma unroll
    for (int off = 32; off; off >>= 1)
        acc += __shfl_down(acc, off, 64);
    if (lane == 0) r[wave] = acc;
    __syncthreads();
    if (tid == 0)
        pred[d] = r[0] + r[1] + r[2] + r[3] + Vb[d];
}

// Kernel 2b: 10 independent segmented log_softmaxes; wave s = segment s.
__global__ void __launch_bounds__(640) k_logsoftmax(
    const float* __restrict__ pred, float* __restrict__ out)
{
    const int seg_a[11] = {0, 13, 26, 39, 48, 52, 65, 78, 91, 100, 104};
    const int s    = threadIdx.x >> 6;
    const int lane = threadIdx.x & 63;
    const int a    = seg_a[s];
    const int len  = seg_a[s + 1] - a;

    float x = (lane < len) ? pred[a + lane] : -INFINITY;
    float m = x;
    #pragma unroll
    for (int off = 32; off; off >>= 1)
        m = fmaxf(m, __shfl_xor(m, off, 64));
    float e = (lane < len) ? expf(x - m) : 0.f;
    float ssum = e;
    #pragma unroll
    for (int off = 32; off; off >>= 1)
        ssum += __shfl_xor(ssum, off, 64);
    if (lane < len) out[a + lane] = x - m - logf(ssum);
}

extern "C" void kernel_launch(void* const* d_in, const int* in_sizes, int n_in,
                              void* d_out, int out_size, void* d_ws, size_t ws_size,
                              hipStream_t stream) {
    const float* line   = (const float*)d_in[0];
    const float* hidden = (const float*)d_in[1];
    const float* Uw     = (const float*)d_in[2];
    const float* Ub     = (const float*)d_in[3];
    const float* Ww     = (const float*)d_in[4];
    const float* Wb     = (const float*)d_in[5];
    const float* Vw     = (const float*)d_in[6];
    const float* Vb     = (const float*)d_in[7];

    float* out  = (float*)d_out;      // [0:104) pred_logsoft, [104:4200) h_t
    float* h_t  = out + D;
    float* pred = (float*)d_ws;       // scratch: 104 floats

    k_hidden<<<H / 4, 256, 0, stream>>>(Uw, hidden, Ub, Ww, line, Wb, h_t);
    k_pred_rows<<<D, 256, 0, stream>>>(Vw, h_t, Vb, pred);
    k_logsoftmax<<<1, 640, 0, stream>>>(pred, out);
}